// Round 5
// baseline (43.180 us; speedup 1.0000x reference)
//
#include <hip/hip_runtime.h>

#define SIG_LEN 2048

// IEEE f32 ops forced via ISA — immune to any fp-contract/fast-math setting.
__device__ __forceinline__ float f_sub(float a, float b) {
    float r; asm("v_sub_f32 %0, %1, %2" : "=v"(r) : "v"(a), "v"(b)); return r;
}
__device__ __forceinline__ float f_mul(float a, float b) {
    float r; asm("v_mul_f32 %0, %1, %2" : "=v"(r) : "v"(a), "v"(b)); return r;
}
__device__ __forceinline__ float f_add(float a, float b) {
    float r; asm("v_add_f32 %0, %1, %2" : "=v"(r) : "v"(a), "v"(b)); return r;
}
__device__ __forceinline__ float f_rndne(float a) {
    float r; asm("v_rndne_f32 %0, %1" : "=v"(r) : "v"(a)); return r;
}
// Hardware reciprocal (the 2.5-ulp fast-division path: a/b -> a * rcp(b)).
__device__ __forceinline__ float f_rcp(float a) {
    float r; asm("v_rcp_f32 %0, %1" : "=v"(r) : "v"(a)); return r;
}

__global__ __launch_bounds__(256) void ParametricInterpolation_kernel(
    const float* __restrict__ x,
    const float* __restrict__ params,
    const float* __restrict__ scaler,
    float* __restrict__ out)
{
    __shared__ float row[SIG_LEN];

    const int b = blockIdx.x;
    const int t = threadIdx.x;

    // ---- stage the row into LDS (coalesced float4 loads) ----
    const float4* xr4  = (const float4*)(x + (size_t)b * SIG_LEN);
    float4*       row4 = (float4*)row;
    row4[t]       = xr4[t];
    row4[t + 256] = xr4[t + 256];

    // ---- scaled params via HW fast division: p = a * v_rcp_f32(b) ----
    // (rcp(1.0) == 1.0 exactly, so the dominant p3 term remains exact.)
    const float p0 = f_mul(params[b * 5 + 0], f_rcp(scaler[0]));
    const float p1 = f_mul(params[b * 5 + 1], f_rcp(scaler[1]));
    const float p2 = f_mul(params[b * 5 + 2], f_rcp(scaler[2]));
    const float p3 = f_mul(params[b * 5 + 3], f_rcp(scaler[3]));
    const float p4 = f_mul(params[b * 5 + 4], f_rcp(scaler[4]));

    __syncthreads();

    float* o = out + (size_t)b * SIG_LEN;

#pragma unroll
    for (int c = 0; c < 2; ++c) {
        const int base = c * 1024 + t * 4;
        float4 r;
#pragma unroll
        for (int j = 0; j < 4; ++j) {
            const float fi = (float)(base + j);

            // Horner, separate mul/add (validated closest pipeline):
            float curve = f_mul(p0, fi);
            curve = f_add(curve, p1);
            curve = f_mul(curve, fi);
            curve = f_add(curve, p2);
            curve = f_mul(curve, fi);
            curve = f_add(curve, p3);
            curve = f_mul(curve, fi);
            curve = f_add(curve, p4);

            const float ci = f_rndne(curve);     // round half to even
            const float k  = f_sub(curve, ci);   // fractional part

            float np_ = fi - ci;                 // exact integer-valued f32
            np_ = fminf(fmaxf(np_, 1.0f), (float)(SIG_LEN - 1));
            const int pos = (int)np_;

            const float x1 = row[pos];
            const float x2 = row[pos - 1];

            const float w  = f_sub(1.0f, k);
            const float a0 = f_mul(x1, w);
            const float a1 = f_mul(x2, k);
            ((float*)&r)[j] = f_add(a0, a1);
        }
        *(float4*)(o + base) = r;
    }
}

extern "C" void kernel_launch(void* const* d_in, const int* in_sizes, int n_in,
                              void* d_out, int out_size, void* d_ws, size_t ws_size,
                              hipStream_t stream) {
    const float* x      = (const float*)d_in[0];
    const float* params = (const float*)d_in[1];
    const float* scaler = (const float*)d_in[2];
    float* out          = (float*)d_out;

    const int B = in_sizes[0] / SIG_LEN;   // 16384
    ParametricInterpolation_kernel<<<B, 256, 0, stream>>>(x, params, scaler, out);
}

// Round 7
// 42.537 us; speedup vs baseline: 1.0151x; 1.0151x over previous
//
#include <hip/hip_runtime.h>

#define SIG_LEN 2048

typedef float f32x4 __attribute__((ext_vector_type(4)));

// IEEE f32 ops forced via ISA — immune to any fp-contract/fast-math setting.
__device__ __forceinline__ float f_sub(float a, float b) {
    float r; asm("v_sub_f32 %0, %1, %2" : "=v"(r) : "v"(a), "v"(b)); return r;
}
__device__ __forceinline__ float f_mul(float a, float b) {
    float r; asm("v_mul_f32 %0, %1, %2" : "=v"(r) : "v"(a), "v"(b)); return r;
}
__device__ __forceinline__ float f_add(float a, float b) {
    float r; asm("v_add_f32 %0, %1, %2" : "=v"(r) : "v"(a), "v"(b)); return r;
}
__device__ __forceinline__ float f_rndne(float a) {
    float r; asm("v_rndne_f32 %0, %1" : "=v"(r) : "v"(a)); return r;
}
// Hardware reciprocal — matches the reference's fast-division (p = a * rcp(b)).
__device__ __forceinline__ float f_rcp(float a) {
    float r; asm("v_rcp_f32 %0, %1" : "=v"(r) : "v"(a)); return r;
}

__global__ __launch_bounds__(256) void ParametricInterpolation_kernel(
    const float* __restrict__ x,
    const float* __restrict__ params,
    const float* __restrict__ scaler,
    float* __restrict__ out)
{
    __shared__ float row[SIG_LEN];

    const int b = blockIdx.x;
    const int t = threadIdx.x;

    // ---- stage the row into LDS (coalesced float4 loads) ----
    const float4* xr4  = (const float4*)(x + (size_t)b * SIG_LEN);
    float4*       row4 = (float4*)row;
    row4[t]       = xr4[t];
    row4[t + 256] = xr4[t + 256];

    // ---- scaled params via HW fast division (bit-exact vs reference) ----
    const float p0 = f_mul(params[b * 5 + 0], f_rcp(scaler[0]));
    const float p1 = f_mul(params[b * 5 + 1], f_rcp(scaler[1]));
    const float p2 = f_mul(params[b * 5 + 2], f_rcp(scaler[2]));
    const float p3 = f_mul(params[b * 5 + 3], f_rcp(scaler[3]));
    const float p4 = f_mul(params[b * 5 + 4], f_rcp(scaler[4]));

    __syncthreads();

    float* o = out + (size_t)b * SIG_LEN;

#pragma unroll
    for (int c = 0; c < 2; ++c) {
        const int base = c * 1024 + t * 4;
        f32x4 r;
#pragma unroll
        for (int j = 0; j < 4; ++j) {
            const float fi = (float)(base + j);

            // Horner, separate mul/add (validated bit-exact pipeline):
            float curve = f_mul(p0, fi);
            curve = f_add(curve, p1);
            curve = f_mul(curve, fi);
            curve = f_add(curve, p2);
            curve = f_mul(curve, fi);
            curve = f_add(curve, p3);
            curve = f_mul(curve, fi);
            curve = f_add(curve, p4);

            const float ci = f_rndne(curve);     // round half to even
            const float k  = f_sub(curve, ci);   // fractional part

            float np_ = fi - ci;                 // exact integer-valued f32
            np_ = fminf(fmaxf(np_, 1.0f), (float)(SIG_LEN - 1));
            const int pos = (int)np_;

            const float x1 = row[pos];
            const float x2 = row[pos - 1];

            const float w  = f_sub(1.0f, k);
            const float a0 = f_mul(x1, w);
            const float a1 = f_mul(x2, k);
            r[j] = f_add(a0, a1);
        }
        // Nontemporal store: stream the output past L3 so x stays L3-resident.
        __builtin_nontemporal_store(r, (f32x4*)(o + base));
    }
}

extern "C" void kernel_launch(void* const* d_in, const int* in_sizes, int n_in,
                              void* d_out, int out_size, void* d_ws, size_t ws_size,
                              hipStream_t stream) {
    const float* x      = (const float*)d_in[0];
    const float* params = (const float*)d_in[1];
    const float* scaler = (const float*)d_in[2];
    float* out          = (float*)d_out;

    const int B = in_sizes[0] / SIG_LEN;   // 16384
    ParametricInterpolation_kernel<<<B, 256, 0, stream>>>(x, params, scaler, out);
}